// Round 5
// baseline (309.703 us; speedup 1.0000x reference)
//
#include <hip/hip_runtime.h>
#include <hip/hip_bf16.h>

typedef unsigned short u16;
typedef __attribute__((ext_vector_type(8))) __bf16 bf16x8;
typedef __attribute__((ext_vector_type(4))) float f32x4;
typedef __attribute__((ext_vector_type(8))) unsigned short ushort8;

#define GM 8192
#define GN 4096
#define GK 4096
#define NT (GK / 64)  // 64 K-tiles of BK=64

__device__ __forceinline__ u16 f2bf(float f) {
  unsigned u = __float_as_uint(f);
  u += 0x7fffu + ((u >> 16) & 1u);
  return (u16)(u >> 16);
}

// ---- kernel 1: W_eff = bf16(W + 2 * (B @ A))   [4096][4096]
__global__ void build_weff(const float* __restrict__ W,
                           const float* __restrict__ lA,
                           const float* __restrict__ lB,
                           u16* __restrict__ Weff) {
  const int o = blockIdx.x;
  float b[8];
#pragma unroll
  for (int r = 0; r < 8; ++r) b[r] = 2.0f * lB[o * 8 + r];
  const float* wrow = W + (size_t)o * GK;
  u16* orow = Weff + (size_t)o * GK;
  for (int d = threadIdx.x * 4; d < GK; d += blockDim.x * 4) {
    float4 w = *reinterpret_cast<const float4*>(wrow + d);
    float a0 = w.x, a1 = w.y, a2 = w.z, a3 = w.w;
#pragma unroll
    for (int r = 0; r < 8; ++r) {
      float4 a = *reinterpret_cast<const float4*>(lA + r * GK + d);
      a0 += b[r] * a.x; a1 += b[r] * a.y; a2 += b[r] * a.z; a3 += b[r] * a.w;
    }
    ushort4 p;
    p.x = f2bf(a0); p.y = f2bf(a1); p.z = f2bf(a2); p.w = f2bf(a3);
    *reinterpret_cast<ushort4*>(orow + d) = p;
  }
}

// ---- kernel 2: x f32 -> bf16
__global__ void cvt_bf16(const float* __restrict__ x, u16* __restrict__ xb) {
  const size_t i = ((size_t)blockIdx.x * blockDim.x + threadIdx.x) * 8;
  float4 v0 = *reinterpret_cast<const float4*>(x + i);
  float4 v1 = *reinterpret_cast<const float4*>(x + i + 4);
  ushort8 o;
  o[0] = f2bf(v0.x); o[1] = f2bf(v0.y); o[2] = f2bf(v0.z); o[3] = f2bf(v0.w);
  o[4] = f2bf(v1.x); o[5] = f2bf(v1.y); o[6] = f2bf(v1.z); o[7] = f2bf(v1.w);
  *reinterpret_cast<ushort8*>(xb + i) = o;
}

// ---- kernel 3: 256x256-tile GEMM, C[m][n] = sum_k A[m][k]*B[n][k]
// 3-bit LDS swizzle (conflict-free, R3). R5: balanced quadrant phases.
// Reads per phase: q0: b01(4)+a03(8)=12, q1: b23(4), q2: a47(8), q3: 0.
// MFMA quadrants: q0: m0-3 x n0-1; q1: m0-3 x n2-3; q2: m4-7 x n2-3;
// q3: m4-7 x n0-1 (bfr0 kept in regs). Staging: q0->B0(t+1), q1->B1(t+1),
// q3->A0+A1(t+2). ONE wait/tile: vmcnt(4) at q3 end (retires B0+B1(t+1),
// leaves A01(t+2) in flight) — both B halves are wave-mapped so ALL of
// tile t must be resident before q0(t).
__device__ __forceinline__ void gload16(const u16* g, u16* l) {
  __builtin_amdgcn_global_load_lds(
      (const __attribute__((address_space(1))) void*)g,
      (__attribute__((address_space(3))) void*)l, 16, 0, 0);
}

#define BAR()                                  \
  do {                                         \
    asm volatile("" ::: "memory");             \
    __builtin_amdgcn_s_barrier();              \
    asm volatile("" ::: "memory");             \
  } while (0)

__global__ __launch_bounds__(512, 2) void gemm256(const u16* __restrict__ Ab,
                                                  const u16* __restrict__ Bb,
                                                  float* __restrict__ C) {
  // [buf][0=A,1=B][row*64 + k], 2*2*16384*2B = 128 KiB
  __shared__ u16 lds[2][2][256 * 64];

  const int tid = threadIdx.x;
  const int wv = tid >> 6;
  const int l = tid & 63;

  // XCD-aware swizzle: 512 blocks, 512 % 8 == 0 -> simple bijective form
  const int nwg = gridDim.x;
  const int cpx = nwg >> 3;
  const int wg = ((int)blockIdx.x & 7) * cpx + ((int)blockIdx.x >> 3);
  const int tm = wg >> 4;   // GN/256 = 16 tiles in N
  const int tn = wg & 15;

  const int wr = wv >> 2;   // 0..1  (M split)
  const int wc = wv & 3;    // 0..3  (N split)

  // --- staging constants ---
  const int srow = (wv << 3) + (l >> 3);
  const int srl = ((wv & 1) << 3) | (l >> 3);          // row bits 0..3
  const int skel = ((l & 7) << 3) ^ ((srl & 0xE) << 2);
  const u16* aG = Ab + (size_t)(tm * 256) * GK;
  const u16* bG = Bb + (size_t)(tn * 256) * GK;

  // --- reader constants ---
  const int frow = l & 15;
  const int fksw = ((l >> 4) << 3) ^ ((frow & 0xE) << 2);
  const int arow = wr * 128 + frow;
  const int brow = wc * 64 + frow;

  // stage half-tile: th = K-tile, r: 0=A0,1=A1,2=B0,3=B1  (2 x gload16/wave)
  auto STAGE = [&](int th, int r) {
    const int k0 = th << 6;
    const u16* src = (r < 2 ? aG : bG) +
                     (size_t)((r & 1) * 128 + srow) * GK + k0 + skel;
    u16* dst = &lds[th & 1][r >> 1][(r & 1) * 8192 + wv * 512];
#pragma unroll
    for (int j = 0; j < 2; ++j)
      gload16(src + (size_t)(j * 64) * GK, dst + j * 4096);
  };

  // prologue: A01(0), B0(0), B1(0), A01(1) = 12 loads; vmcnt(4) retires
  // tile-0 entirely, leaves A01(1) in flight.
  STAGE(0, 0); STAGE(0, 1); STAGE(0, 2); STAGE(0, 3);
  STAGE(1, 0); STAGE(1, 1);

  f32x4 acc[8][4] = {};
  bf16x8 af[4][2], bfr0[2][2], bfr1[2][2];

  asm volatile("s_waitcnt vmcnt(4)" ::: "memory");
  BAR();

  for (int t = 0; t < NT; ++t) {
    const u16* A = &lds[t & 1][0][0];
    const u16* B = &lds[t & 1][1][0];
#pragma unroll
    for (int q = 0; q < 4; ++q) {
      // --- register subtile loads (ds_read_b128), balanced 12/4/8/0 ---
      if (q == 0) {
#pragma unroll
        for (int n = 0; n < 2; ++n)
#pragma unroll
          for (int s = 0; s < 2; ++s)
            bfr0[n][s] = *reinterpret_cast<const bf16x8*>(
                B + (brow + n * 16) * 64 + (fksw ^ (s << 5)));
#pragma unroll
        for (int m = 0; m < 4; ++m)
#pragma unroll
          for (int s = 0; s < 2; ++s)
            af[m][s] = *reinterpret_cast<const bf16x8*>(
                A + (arow + m * 16) * 64 + (fksw ^ (s << 5)));
      } else if (q == 1) {
#pragma unroll
        for (int n = 0; n < 2; ++n)
#pragma unroll
          for (int s = 0; s < 2; ++s)
            bfr1[n][s] = *reinterpret_cast<const bf16x8*>(
                B + (brow + (n + 2) * 16) * 64 + (fksw ^ (s << 5)));
      } else if (q == 2) {
#pragma unroll
        for (int m = 0; m < 4; ++m)
#pragma unroll
          for (int s = 0; s < 2; ++s)
            af[m][s] = *reinterpret_cast<const bf16x8*>(
                A + (arow + (m + 4) * 16) * 64 + (fksw ^ (s << 5)));
      }
      // --- stage: q0->B0(t+1), q1->B1(t+1), q3->A0+A1(t+2) ---
      if (q == 0) { if (t + 1 < NT) STAGE(t + 1, 2); }
      else if (q == 1) { if (t + 1 < NT) STAGE(t + 1, 3); }
      else if (q == 3) { if (t + 2 < NT) { STAGE(t + 2, 0); STAGE(t + 2, 1); } }

      BAR();
      __builtin_amdgcn_s_setprio(1);
      {
        const int mo = (q >= 2) ? 4 : 0;          // m-offset of quadrant
        const int no = (q == 1 || q == 2) ? 2 : 0; // n-offset of quadrant
#pragma unroll
        for (int m = 0; m < 4; ++m)
#pragma unroll
          for (int n = 0; n < 2; ++n)
#pragma unroll
            for (int s = 0; s < 2; ++s)
              acc[mo + m][no + n] = __builtin_amdgcn_mfma_f32_16x16x32_bf16(
                  af[m][s], (no ? bfr1 : bfr0)[n][s], acc[mo + m][no + n],
                  0, 0, 0);
      }
      __builtin_amdgcn_s_setprio(0);
      // ONE counted wait per K-tile at q3: retire B0+B1(t+1), keep A01(t+2)
      if (q == 3) {
        if (t < NT - 2)
          asm volatile("s_waitcnt vmcnt(4)" ::: "memory");
        else if (t == NT - 2)
          asm volatile("s_waitcnt vmcnt(0)" ::: "memory");
      }
      BAR();
    }
  }

  // epilogue: C/D layout col = l&15, row = 4*(l>>4)+j
  const int orow = tm * 256 + wr * 128 + ((l >> 4) << 2);
  const int ocol = tn * 256 + wc * 64 + (l & 15);
#pragma unroll
  for (int m = 0; m < 8; ++m)
#pragma unroll
    for (int n = 0; n < 4; ++n) {
      float* cp = C + (size_t)(orow + m * 16) * GN + (ocol + n * 16);
#pragma unroll
      for (int j = 0; j < 4; ++j) cp[(size_t)j * GN] = acc[m][n][j];
    }
}

extern "C" void kernel_launch(void* const* d_in, const int* in_sizes, int n_in,
                              void* d_out, int out_size, void* d_ws, size_t ws_size,
                              hipStream_t stream) {
  const float* x  = (const float*)d_in[0];
  const float* W  = (const float*)d_in[1];
  const float* lA = (const float*)d_in[2];
  const float* lB = (const float*)d_in[3];
  float* out = (float*)d_out;

  u16* weff = (u16*)d_ws;
  u16* xb = (u16*)((char*)d_ws + (size_t)GN * GK * sizeof(u16));

  build_weff<<<GN, 256, 0, stream>>>(W, lA, lB, weff);
  cvt_bf16<<<(size_t)GM * GK / (256 * 8), 256, 0, stream>>>(x, xb);
  gemm256<<<(GM / 256) * (GN / 256), 512, 0, stream>>>(xb, weff, out);
}

// Round 6
// 299.100 us; speedup vs baseline: 1.0355x; 1.0355x over previous
//
#include <hip/hip_runtime.h>
#include <hip/hip_bf16.h>

typedef unsigned short u16;
typedef __attribute__((ext_vector_type(8))) __bf16 bf16x8;
typedef __attribute__((ext_vector_type(4))) float f32x4;
typedef __attribute__((ext_vector_type(8))) unsigned short ushort8;

#define GM 8192
#define GN 4096
#define GK 4096
#define NT (GK / 64)  // 64 K-tiles of BK=64

__device__ __forceinline__ u16 f2bf(float f) {
  unsigned u = __float_as_uint(f);
  u += 0x7fffu + ((u >> 16) & 1u);
  return (u16)(u >> 16);
}

// ---- kernel 1: W_eff = bf16(W + 2 * (B @ A))   [4096][4096]
__global__ void build_weff(const float* __restrict__ W,
                           const float* __restrict__ lA,
                           const float* __restrict__ lB,
                           u16* __restrict__ Weff) {
  const int o = blockIdx.x;
  float b[8];
#pragma unroll
  for (int r = 0; r < 8; ++r) b[r] = 2.0f * lB[o * 8 + r];
  const float* wrow = W + (size_t)o * GK;
  u16* orow = Weff + (size_t)o * GK;
  for (int d = threadIdx.x * 4; d < GK; d += blockDim.x * 4) {
    float4 w = *reinterpret_cast<const float4*>(wrow + d);
    float a0 = w.x, a1 = w.y, a2 = w.z, a3 = w.w;
#pragma unroll
    for (int r = 0; r < 8; ++r) {
      float4 a = *reinterpret_cast<const float4*>(lA + r * GK + d);
      a0 += b[r] * a.x; a1 += b[r] * a.y; a2 += b[r] * a.z; a3 += b[r] * a.w;
    }
    ushort4 p;
    p.x = f2bf(a0); p.y = f2bf(a1); p.z = f2bf(a2); p.w = f2bf(a3);
    *reinterpret_cast<ushort4*>(orow + d) = p;
  }
}

// ---- kernel 2: x f32 -> bf16
__global__ void cvt_bf16(const float* __restrict__ x, u16* __restrict__ xb) {
  const size_t i = ((size_t)blockIdx.x * blockDim.x + threadIdx.x) * 8;
  float4 v0 = *reinterpret_cast<const float4*>(x + i);
  float4 v1 = *reinterpret_cast<const float4*>(x + i + 4);
  ushort8 o;
  o[0] = f2bf(v0.x); o[1] = f2bf(v0.y); o[2] = f2bf(v0.z); o[3] = f2bf(v0.w);
  o[4] = f2bf(v1.x); o[5] = f2bf(v1.y); o[6] = f2bf(v1.z); o[7] = f2bf(v1.w);
  *reinterpret_cast<ushort8*>(xb + i) = o;
}

// ---- kernel 3: 256x256-tile GEMM, C[m][n] = sum_k A[m][k]*B[n][k]
// R6: ONE barrier per K-tile, 1-deep staging, no manual lgkm waits.
// Diagnosis (R5): 8 barriers/tile forced lockstep read->wait->MFMA phases;
// measured 4980 cyc/tile = MFMA(2483) + LDS(2800) fully SERIALIZED.
// With 1-deep staging (stage t+1 into buf[t^1] only), the tile body has
// zero intra-tile hazards -> drop all intra-tile barriers; the compiler's
// counted lgkmcnt interleaves 24 ds_reads with 64 MFMA per wave, and waves
// de-lockstep so one wave's MFMA covers another's reads.
// 3-bit LDS swizzle kept (conflict-free, R3). XCD swizzle kept.
__device__ __forceinline__ void gload16(const u16* g, u16* l) {
  __builtin_amdgcn_global_load_lds(
      (const __attribute__((address_space(1))) void*)g,
      (__attribute__((address_space(3))) void*)l, 16, 0, 0);
}

#define BAR()                                  \
  do {                                         \
    asm volatile("" ::: "memory");             \
    __builtin_amdgcn_s_barrier();              \
    asm volatile("" ::: "memory");             \
  } while (0)

__global__ __launch_bounds__(512, 2) void gemm256(const u16* __restrict__ Ab,
                                                  const u16* __restrict__ Bb,
                                                  float* __restrict__ C) {
  // [buf][0=A,1=B][row*64 + k], 2*2*16384*2B = 128 KiB
  __shared__ u16 lds[2][2][256 * 64];

  const int tid = threadIdx.x;
  const int wv = tid >> 6;
  const int l = tid & 63;

  // XCD-aware swizzle: 512 blocks, 512 % 8 == 0 -> simple bijective form
  const int nwg = gridDim.x;
  const int cpx = nwg >> 3;
  const int wg = ((int)blockIdx.x & 7) * cpx + ((int)blockIdx.x >> 3);
  const int tm = wg >> 4;   // GN/256 = 16 tiles in N
  const int tn = wg & 15;

  const int wr = wv >> 2;   // 0..1  (M split)
  const int wc = wv & 3;    // 0..3  (N split)

  // --- staging constants ---
  const int srow = (wv << 3) + (l >> 3);
  const int srl = ((wv & 1) << 3) | (l >> 3);          // row bits 0..3
  const int skel = ((l & 7) << 3) ^ ((srl & 0xE) << 2);
  const u16* aG = Ab + (size_t)(tm * 256) * GK;
  const u16* bG = Bb + (size_t)(tn * 256) * GK;

  // --- reader constants ---
  const int frow = l & 15;
  const int fksw = ((l >> 4) << 3) ^ ((frow & 0xE) << 2);
  const int arow = wr * 128 + frow;
  const int brow = wc * 64 + frow;

  // stage half-tile: th = K-tile, r: 0=A0,1=A1,2=B0,3=B1  (2 x gload16/wave)
  auto STAGE = [&](int th, int r) {
    const int k0 = th << 6;
    const u16* src = (r < 2 ? aG : bG) +
                     (size_t)((r & 1) * 128 + srow) * GK + k0 + skel;
    u16* dst = &lds[th & 1][r >> 1][(r & 1) * 8192 + wv * 512];
#pragma unroll
    for (int j = 0; j < 2; ++j)
      gload16(src + (size_t)(j * 64) * GK, dst + j * 4096);
  };

  // prologue: stage tile 0 only (1-deep pipeline)
  STAGE(0, 0); STAGE(0, 1); STAGE(0, 2); STAGE(0, 3);

  f32x4 acc[8][4] = {};
  bf16x8 af_lo[4][2], af_hi[4][2], bfr0[2][2], bfr1[2][2];

  for (int t = 0; t < NT; ++t) {
    // tile-boundary sync: wave's own staging of buf(t) complete (vmcnt),
    // then barrier = everyone done staging t AND done reading t-1.
    asm volatile("s_waitcnt vmcnt(0)" ::: "memory");
    BAR();

    const u16* A = &lds[t & 1][0][0];
    const u16* B = &lds[t & 1][1][0];

    // issue next tile's staging first (longest latency, waited next iter)
    if (t + 1 < NT) {
      STAGE(t + 1, 0); STAGE(t + 1, 1); STAGE(t + 1, 2); STAGE(t + 1, 3);
    }

    // --- free-flow tile body: compiler interleaves reads & MFMA ---
    // Q0: m0-3 x n0-1
#pragma unroll
    for (int n = 0; n < 2; ++n)
#pragma unroll
      for (int s = 0; s < 2; ++s)
        bfr0[n][s] = *reinterpret_cast<const bf16x8*>(
            B + (brow + n * 16) * 64 + (fksw ^ (s << 5)));
#pragma unroll
    for (int m = 0; m < 4; ++m)
#pragma unroll
      for (int s = 0; s < 2; ++s)
        af_lo[m][s] = *reinterpret_cast<const bf16x8*>(
            A + (arow + m * 16) * 64 + (fksw ^ (s << 5)));
    __builtin_amdgcn_s_setprio(1);
#pragma unroll
    for (int m = 0; m < 4; ++m)
#pragma unroll
      for (int n = 0; n < 2; ++n)
#pragma unroll
        for (int s = 0; s < 2; ++s)
          acc[m][n] = __builtin_amdgcn_mfma_f32_16x16x32_bf16(
              af_lo[m][s], bfr0[n][s], acc[m][n], 0, 0, 0);
    __builtin_amdgcn_s_setprio(0);

    // Q1: m0-3 x n2-3
#pragma unroll
    for (int n = 0; n < 2; ++n)
#pragma unroll
      for (int s = 0; s < 2; ++s)
        bfr1[n][s] = *reinterpret_cast<const bf16x8*>(
            B + (brow + (n + 2) * 16) * 64 + (fksw ^ (s << 5)));
    __builtin_amdgcn_s_setprio(1);
#pragma unroll
    for (int m = 0; m < 4; ++m)
#pragma unroll
      for (int n = 0; n < 2; ++n)
#pragma unroll
        for (int s = 0; s < 2; ++s)
          acc[m][n + 2] = __builtin_amdgcn_mfma_f32_16x16x32_bf16(
              af_lo[m][s], bfr1[n][s], acc[m][n + 2], 0, 0, 0);
    __builtin_amdgcn_s_setprio(0);

    // Q2: m4-7 x n2-3
#pragma unroll
    for (int m = 0; m < 4; ++m)
#pragma unroll
      for (int s = 0; s < 2; ++s)
        af_hi[m][s] = *reinterpret_cast<const bf16x8*>(
            A + (arow + (m + 4) * 16) * 64 + (fksw ^ (s << 5)));
    __builtin_amdgcn_s_setprio(1);
#pragma unroll
    for (int m = 0; m < 4; ++m)
#pragma unroll
      for (int n = 0; n < 2; ++n)
#pragma unroll
        for (int s = 0; s < 2; ++s)
          acc[m + 4][n + 2] = __builtin_amdgcn_mfma_f32_16x16x32_bf16(
              af_hi[m][s], bfr1[n][s], acc[m + 4][n + 2], 0, 0, 0);
    __builtin_amdgcn_s_setprio(0);

    // Q3: m4-7 x n0-1 (all operands already resident)
    __builtin_amdgcn_s_setprio(1);
#pragma unroll
    for (int m = 0; m < 4; ++m)
#pragma unroll
      for (int n = 0; n < 2; ++n)
#pragma unroll
        for (int s = 0; s < 2; ++s)
          acc[m + 4][n] = __builtin_amdgcn_mfma_f32_16x16x32_bf16(
              af_hi[m][s], bfr0[n][s], acc[m + 4][n], 0, 0, 0);
    __builtin_amdgcn_s_setprio(0);
  }

  // epilogue: C/D layout col = l&15, row = 4*(l>>4)+j
  const int orow = tm * 256 + wr * 128 + ((l >> 4) << 2);
  const int ocol = tn * 256 + wc * 64 + (l & 15);
#pragma unroll
  for (int m = 0; m < 8; ++m)
#pragma unroll
    for (int n = 0; n < 4; ++n) {
      float* cp = C + (size_t)(orow + m * 16) * GN + (ocol + n * 16);
#pragma unroll
      for (int j = 0; j < 4; ++j) cp[(size_t)j * GN] = acc[m][n][j];
    }
}

extern "C" void kernel_launch(void* const* d_in, const int* in_sizes, int n_in,
                              void* d_out, int out_size, void* d_ws, size_t ws_size,
                              hipStream_t stream) {
  const float* x  = (const float*)d_in[0];
  const float* W  = (const float*)d_in[1];
  const float* lA = (const float*)d_in[2];
  const float* lB = (const float*)d_in[3];
  float* out = (float*)d_out;

  u16* weff = (u16*)d_ws;
  u16* xb = (u16*)((char*)d_ws + (size_t)GN * GK * sizeof(u16));

  build_weff<<<GN, 256, 0, stream>>>(W, lA, lB, weff);
  cvt_bf16<<<(size_t)GM * GK / (256 * 8), 256, 0, stream>>>(x, xb);
  gemm256<<<(GM / 256) * (GN / 256), 512, 0, stream>>>(xb, weff, out);
}

// Round 7
// 292.204 us; speedup vs baseline: 1.0599x; 1.0236x over previous
//
#include <hip/hip_runtime.h>
#include <hip/hip_bf16.h>

typedef unsigned short u16;
typedef __attribute__((ext_vector_type(8))) __bf16 bf16x8;
typedef __attribute__((ext_vector_type(4))) float f32x4;
typedef __attribute__((ext_vector_type(8))) unsigned short ushort8;

#define GM 8192
#define GN 4096
#define GK 4096
#define NT (GK / 64)  // 64 K-tiles of BK=64

__device__ __forceinline__ u16 f2bf(float f) {
  unsigned u = __float_as_uint(f);
  u += 0x7fffu + ((u >> 16) & 1u);
  return (u16)(u >> 16);
}

// ---- kernel 1: W_eff = bf16(W + 2 * (B @ A))   [4096][4096]
__global__ void build_weff(const float* __restrict__ W,
                           const float* __restrict__ lA,
                           const float* __restrict__ lB,
                           u16* __restrict__ Weff) {
  const int o = blockIdx.x;
  float b[8];
#pragma unroll
  for (int r = 0; r < 8; ++r) b[r] = 2.0f * lB[o * 8 + r];
  const float* wrow = W + (size_t)o * GK;
  u16* orow = Weff + (size_t)o * GK;
  for (int d = threadIdx.x * 4; d < GK; d += blockDim.x * 4) {
    float4 w = *reinterpret_cast<const float4*>(wrow + d);
    float a0 = w.x, a1 = w.y, a2 = w.z, a3 = w.w;
#pragma unroll
    for (int r = 0; r < 8; ++r) {
      float4 a = *reinterpret_cast<const float4*>(lA + r * GK + d);
      a0 += b[r] * a.x; a1 += b[r] * a.y; a2 += b[r] * a.z; a3 += b[r] * a.w;
    }
    ushort4 p;
    p.x = f2bf(a0); p.y = f2bf(a1); p.z = f2bf(a2); p.w = f2bf(a3);
    *reinterpret_cast<ushort4*>(orow + d) = p;
  }
}

// ---- kernel 2: x f32 -> bf16
__global__ void cvt_bf16(const float* __restrict__ x, u16* __restrict__ xb) {
  const size_t i = ((size_t)blockIdx.x * blockDim.x + threadIdx.x) * 8;
  float4 v0 = *reinterpret_cast<const float4*>(x + i);
  float4 v1 = *reinterpret_cast<const float4*>(x + i + 4);
  ushort8 o;
  o[0] = f2bf(v0.x); o[1] = f2bf(v0.y); o[2] = f2bf(v0.z); o[3] = f2bf(v0.w);
  o[4] = f2bf(v1.x); o[5] = f2bf(v1.y); o[6] = f2bf(v1.z); o[7] = f2bf(v1.w);
  *reinterpret_cast<ushort8*>(xb + i) = o;
}

// ---- kernel 3: 256x256-tile GEMM, C[m][n] = sum_k A[m][k]*B[n][k]
// R7: all-reads-first tile body. Diagnosis (R6): per-quadrant read->MFMA
// still leaves ~1200 cyc/tile of pipe-idle (all waves lgkm-wait together,
// then all MFMA together). Fix: issue all 24 ds_read_b128 up front into a
// full double fragment set -> LDS queue is 192-deep per CU right after the
// barrier (LDS pipe 100% busy), MFMA streams start as soon as each wave's
// early reads retire (compiler's counted lgkmcnt), consumption order =
// issue order (bfr0, af_lo -> Q0; bfr1 -> Q1; af_hi -> Q2/Q3).
// One barrier + one vmcnt(0) per K-tile; 1-deep staging (R6).
// 3-bit LDS swizzle kept (conflict-free, R3). XCD swizzle kept.
__device__ __forceinline__ void gload16(const u16* g, u16* l) {
  __builtin_amdgcn_global_load_lds(
      (const __attribute__((address_space(1))) void*)g,
      (__attribute__((address_space(3))) void*)l, 16, 0, 0);
}

#define BAR()                                  \
  do {                                         \
    asm volatile("" ::: "memory");             \
    __builtin_amdgcn_s_barrier();              \
    asm volatile("" ::: "memory");             \
  } while (0)

__global__ __launch_bounds__(512, 2) void gemm256(const u16* __restrict__ Ab,
                                                  const u16* __restrict__ Bb,
                                                  float* __restrict__ C) {
  // [buf][0=A,1=B][row*64 + k], 2*2*16384*2B = 128 KiB
  __shared__ u16 lds[2][2][256 * 64];

  const int tid = threadIdx.x;
  const int wv = tid >> 6;
  const int l = tid & 63;

  // XCD-aware swizzle: 512 blocks, 512 % 8 == 0 -> simple bijective form
  const int nwg = gridDim.x;
  const int cpx = nwg >> 3;
  const int wg = ((int)blockIdx.x & 7) * cpx + ((int)blockIdx.x >> 3);
  const int tm = wg >> 4;   // GN/256 = 16 tiles in N
  const int tn = wg & 15;

  const int wr = wv >> 2;   // 0..1  (M split)
  const int wc = wv & 3;    // 0..3  (N split)

  // --- staging constants ---
  const int srow = (wv << 3) + (l >> 3);
  const int srl = ((wv & 1) << 3) | (l >> 3);          // row bits 0..3
  const int skel = ((l & 7) << 3) ^ ((srl & 0xE) << 2);
  const u16* aG = Ab + (size_t)(tm * 256) * GK;
  const u16* bG = Bb + (size_t)(tn * 256) * GK;

  // --- reader constants ---
  const int frow = l & 15;
  const int fksw = ((l >> 4) << 3) ^ ((frow & 0xE) << 2);
  const int arow = wr * 128 + frow;
  const int brow = wc * 64 + frow;

  // stage half-tile: th = K-tile, r: 0=A0,1=A1,2=B0,3=B1  (2 x gload16/wave)
  auto STAGE = [&](int th, int r) {
    const int k0 = th << 6;
    const u16* src = (r < 2 ? aG : bG) +
                     (size_t)((r & 1) * 128 + srow) * GK + k0 + skel;
    u16* dst = &lds[th & 1][r >> 1][(r & 1) * 8192 + wv * 512];
#pragma unroll
    for (int j = 0; j < 2; ++j)
      gload16(src + (size_t)(j * 64) * GK, dst + j * 4096);
  };

  // prologue: stage tile 0 only (1-deep pipeline)
  STAGE(0, 0); STAGE(0, 1); STAGE(0, 2); STAGE(0, 3);

  f32x4 acc[8][4] = {};
  bf16x8 af_lo[4][2], af_hi[4][2], bfr0[2][2], bfr1[2][2];

  for (int t = 0; t < NT; ++t) {
    // tile-boundary sync: own staging of buf(t) complete (vmcnt), then
    // barrier = everyone done staging t AND done reading t-1.
    asm volatile("s_waitcnt vmcnt(0)" ::: "memory");
    BAR();

    const u16* A = &lds[t & 1][0][0];
    const u16* B = &lds[t & 1][1][0];

    // ---- ALL 24 ds_read_b128 first, in consumption order ----
#pragma unroll
    for (int n = 0; n < 2; ++n)
#pragma unroll
      for (int s = 0; s < 2; ++s)
        bfr0[n][s] = *reinterpret_cast<const bf16x8*>(
            B + (brow + n * 16) * 64 + (fksw ^ (s << 5)));
#pragma unroll
    for (int m = 0; m < 4; ++m)
#pragma unroll
      for (int s = 0; s < 2; ++s)
        af_lo[m][s] = *reinterpret_cast<const bf16x8*>(
            A + (arow + m * 16) * 64 + (fksw ^ (s << 5)));
#pragma unroll
    for (int n = 0; n < 2; ++n)
#pragma unroll
      for (int s = 0; s < 2; ++s)
        bfr1[n][s] = *reinterpret_cast<const bf16x8*>(
            B + (brow + (n + 2) * 16) * 64 + (fksw ^ (s << 5)));
#pragma unroll
    for (int m = 0; m < 4; ++m)
#pragma unroll
      for (int s = 0; s < 2; ++s)
        af_hi[m][s] = *reinterpret_cast<const bf16x8*>(
            A + (arow + (m + 4) * 16) * 64 + (fksw ^ (s << 5)));

    // staging for t+1 (VMEM pipe; LDS-writes land during MFMA stream)
    if (t + 1 < NT) {
      STAGE(t + 1, 0); STAGE(t + 1, 1); STAGE(t + 1, 2); STAGE(t + 1, 3);
    }

    // ---- 64 MFMA; counted lgkm waits pipeline against the read stream ----
    __builtin_amdgcn_s_setprio(1);
    // Q0: m0-3 x n0-1 (bfr0, af_lo — earliest reads)
#pragma unroll
    for (int m = 0; m < 4; ++m)
#pragma unroll
      for (int n = 0; n < 2; ++n)
#pragma unroll
        for (int s = 0; s < 2; ++s)
          acc[m][n] = __builtin_amdgcn_mfma_f32_16x16x32_bf16(
              af_lo[m][s], bfr0[n][s], acc[m][n], 0, 0, 0);
    // Q1: m0-3 x n2-3 (bfr1)
#pragma unroll
    for (int m = 0; m < 4; ++m)
#pragma unroll
      for (int n = 0; n < 2; ++n)
#pragma unroll
        for (int s = 0; s < 2; ++s)
          acc[m][n + 2] = __builtin_amdgcn_mfma_f32_16x16x32_bf16(
              af_lo[m][s], bfr1[n][s], acc[m][n + 2], 0, 0, 0);
    // Q2: m4-7 x n2-3 (af_hi — latest reads)
#pragma unroll
    for (int m = 0; m < 4; ++m)
#pragma unroll
      for (int n = 0; n < 2; ++n)
#pragma unroll
        for (int s = 0; s < 2; ++s)
          acc[m + 4][n + 2] = __builtin_amdgcn_mfma_f32_16x16x32_bf16(
              af_hi[m][s], bfr1[n][s], acc[m + 4][n + 2], 0, 0, 0);
    // Q3: m4-7 x n0-1 (all resident)
#pragma unroll
    for (int m = 0; m < 4; ++m)
#pragma unroll
      for (int n = 0; n < 2; ++n)
#pragma unroll
        for (int s = 0; s < 2; ++s)
          acc[m + 4][n] = __builtin_amdgcn_mfma_f32_16x16x32_bf16(
              af_hi[m][s], bfr0[n][s], acc[m + 4][n], 0, 0, 0);
    __builtin_amdgcn_s_setprio(0);
  }

  // epilogue: C/D layout col = l&15, row = 4*(l>>4)+j
  const int orow = tm * 256 + wr * 128 + ((l >> 4) << 2);
  const int ocol = tn * 256 + wc * 64 + (l & 15);
#pragma unroll
  for (int m = 0; m < 8; ++m)
#pragma unroll
    for (int n = 0; n < 4; ++n) {
      float* cp = C + (size_t)(orow + m * 16) * GN + (ocol + n * 16);
#pragma unroll
      for (int j = 0; j < 4; ++j) cp[(size_t)j * GN] = acc[m][n][j];
    }
}

extern "C" void kernel_launch(void* const* d_in, const int* in_sizes, int n_in,
                              void* d_out, int out_size, void* d_ws, size_t ws_size,
                              hipStream_t stream) {
  const float* x  = (const float*)d_in[0];
  const float* W  = (const float*)d_in[1];
  const float* lA = (const float*)d_in[2];
  const float* lB = (const float*)d_in[3];
  float* out = (float*)d_out;

  u16* weff = (u16*)d_ws;
  u16* xb = (u16*)((char*)d_ws + (size_t)GN * GK * sizeof(u16));

  build_weff<<<GN, 256, 0, stream>>>(W, lA, lB, weff);
  cvt_bf16<<<(size_t)GM * GK / (256 * 8), 256, 0, stream>>>(x, xb);
  gemm256<<<(GM / 256) * (GN / 256), 512, 0, stream>>>(xb, weff, out);
}